// Round 13
// baseline (120.457 us; speedup 1.0000x reference)
//
#include <hip/hip_runtime.h>
#include <math.h>

#define N_NODES 100000
#define N_EDGES 3200000
#define IN_FEAT 256
#define HEADS 2
#define NC 8
#define FH 16               // HEADS*NC
#define NEG_SLOPE 0.2f
#define EPSF 1e-15f

// Bucketed partition: 64 dsts per bucket.
#define BSH 6
#define BUCK_W 64
#define DLM 63
#define NBUCK ((N_NODES + BUCK_W - 1) / BUCK_W)   // 1563
#define B1 640                                    // partition chunks (8 XCDs x 80)
#define EPB (N_EDGES / B1)                        // 5000 edges/chunk (exact)

// Fused sort+agg: LDS capacity per bucket (mean 2048, sd 45; +11 sd margin).
#define SORT_CAP 2560
#define RCAP (SORT_CAP / 256)    // 10 register-cached records per thread
#define TPD 4                    // threads per dst in agg phase

typedef float f32x4 __attribute__((ext_vector_type(4)));
typedef short bf16x8 __attribute__((ext_vector_type(8)));

__device__ __forceinline__ unsigned short f2bf(float f) {
    unsigned u = __float_as_uint(f);
    u += 0x7FFFu + ((u >> 16) & 1u);      // round-to-nearest-even
    return (unsigned short)(u >> 16);
}
__device__ __forceinline__ float bflo(unsigned u) { return __uint_as_float(u << 16); }
__device__ __forceinline__ float bfhi(unsigned u) { return __uint_as_float(u & 0xFFFF0000u); }

// XCD-grouped bijective chunk map (8 XCDs x 80 chunks): each XCD owns a
// contiguous chunk range -> its packed-runs in every bucket segment are
// contiguous and L2-local (no cross-XCD dirty-line sharing).
__device__ __forceinline__ int chunk_of_block(int bid) {
    return (bid & 7) * (B1 / 8) + (bid >> 3);
}

// ---------------------------------------------------------------------------
// Kernel 1 (MFMA): one wave per 16 nodes; D[16x32] = bf16(x)@bf16([W|Wres]).
__global__ __launch_bounds__(256) void k_node(
        const float* __restrict__ x, const float* __restrict__ W,
        const float* __restrict__ Wres, const float* __restrict__ attn_l,
        const float* __restrict__ attn_r,
        unsigned short* __restrict__ featb, float* __restrict__ res,
        float* __restrict__ el, float* __restrict__ er) {
    int wid = (blockIdx.x * 256 + threadIdx.x) >> 6;   // global wave id
    int n0 = wid * 16;
    if (n0 >= N_NODES) return;                          // N_NODES % 16 == 0
    int l   = threadIdx.x & 63;
    int col = l & 15;
    int g   = l >> 4;

    bf16x8 bw[8], bq[8];
    #pragma unroll
    for (int kk = 0; kk < 8; kk++) {
        #pragma unroll
        for (int j = 0; j < 8; j++) {
            int k = kk * 32 + g * 8 + j;
            bw[kk][j] = (short)f2bf(W[k * FH + col]);
            bq[kk][j] = (short)f2bf(Wres[k * FH + col]);
        }
    }

    const float* xr = x + (size_t)(n0 + col) * IN_FEAT;
    f32x4 acc0 = {0.f, 0.f, 0.f, 0.f};
    f32x4 acc1 = {0.f, 0.f, 0.f, 0.f};
    float ss = 0.f;
    #pragma unroll
    for (int kk = 0; kk < 8; kk++) {
        float4 v0 = *(const float4*)(xr + kk * 32 + g * 8);
        float4 v1 = *(const float4*)(xr + kk * 32 + g * 8 + 4);
        ss += v0.x * v0.x + v0.y * v0.y + v0.z * v0.z + v0.w * v0.w
            + v1.x * v1.x + v1.y * v1.y + v1.z * v1.z + v1.w * v1.w;
        bf16x8 a;
        a[0] = (short)f2bf(v0.x); a[1] = (short)f2bf(v0.y);
        a[2] = (short)f2bf(v0.z); a[3] = (short)f2bf(v0.w);
        a[4] = (short)f2bf(v1.x); a[5] = (short)f2bf(v1.y);
        a[6] = (short)f2bf(v1.z); a[7] = (short)f2bf(v1.w);
        acc0 = __builtin_amdgcn_mfma_f32_16x16x32_bf16(a, bw[kk], acc0, 0, 0, 0);
        acc1 = __builtin_amdgcn_mfma_f32_16x16x32_bf16(a, bq[kk], acc1, 0, 0, 0);
    }

    ss += __shfl_xor(ss, 16);
    ss += __shfl_xor(ss, 32);
    float norm = fmaxf(sqrtf(ss), EPSF);
    float z = fminf(norm, 1.f - 1e-7f);
    float at = 0.5f * (log1pf(z) - log1pf(-z));   // artanh(clip)
    float scale = at / norm;

    float alc = attn_l[col], arc = attn_r[col];

    #pragma unroll
    for (int i = 0; i < 4; i++) {
        int ri = g * 4 + i;
        float s_i = __shfl(scale, ri);
        int nr = n0 + ri;
        float f_i = acc0[i] * s_i;
        float q_i = acc1[i] * s_i;
        featb[(size_t)nr * FH + col] = f2bf(f_i);
        res  [(size_t)nr * FH + col] = q_i;
        float pl = f_i * alc, pr = f_i * arc;
        float pl0 = (col < 8) ? pl : 0.f, pl1 = (col < 8) ? 0.f : pl;
        float pr0 = (col < 8) ? pr : 0.f, pr1 = (col < 8) ? 0.f : pr;
        #pragma unroll
        for (int m = 1; m < 16; m <<= 1) {
            pl0 += __shfl_xor(pl0, m); pl1 += __shfl_xor(pl1, m);
            pr0 += __shfl_xor(pr0, m); pr1 += __shfl_xor(pr1, m);
        }
        if (col == 0) {
            *(float2*)(el + nr * 2) = make_float2(pl0, pl1);
            *(float2*)(er + nr * 2) = make_float2(pr0, pr1);
        }
    }
}

// ---------------------------------------------------------------------------
// Kernel 2: per-chunk bucket histogram (LDS atomics only)
__global__ __launch_bounds__(256) void k_count(const int* __restrict__ ei,
                                               int* __restrict__ hist_g) {
    __shared__ int h[NBUCK];
    for (int i = threadIdx.x; i < NBUCK; i += 256) h[i] = 0;
    __syncthreads();
    int chunk = chunk_of_block(blockIdx.x);
    const int4* dp = (const int4*)(ei + N_EDGES + (size_t)chunk * EPB);
    for (int i = threadIdx.x; i < EPB / 4; i += 256) {
        int4 d = dp[i];
        atomicAdd(&h[d.x >> BSH], 1);
        atomicAdd(&h[d.y >> BSH], 1);
        atomicAdd(&h[d.z >> BSH], 1);
        atomicAdd(&h[d.w >> BSH], 1);
    }
    __syncthreads();
    int* outp = hist_g + (size_t)blockIdx.x * 0 + (size_t)chunk * NBUCK;
    for (int i = threadIdx.x; i < NBUCK; i += 256) outp[i] = h[i];
}

// ---------------------------------------------------------------------------
// Kernel 3: per-bucket exclusive scan over the B1 chunks (in place) + totals.
__global__ __launch_bounds__(64) void k_scan1(int* __restrict__ hist_g,
                                              int* __restrict__ btot) {
    __shared__ int sm[64];
    int bucket = blockIdx.x;
    int t = threadIdx.x;
    int carry = 0;
    for (int base = 0; base < B1; base += 64) {
        int blk = base + t;
        int v = hist_g[(size_t)blk * NBUCK + bucket];       // B1 % 64 == 0
        __syncthreads();
        sm[t] = v;
        __syncthreads();
        for (int off = 1; off < 64; off <<= 1) {
            int u = (t >= off) ? sm[t - off] : 0;
            __syncthreads();
            sm[t] += u;
            __syncthreads();
        }
        hist_g[(size_t)blk * NBUCK + bucket] = carry + sm[t] - v;
        carry += sm[63];
    }
    if (t == 0) btot[bucket] = carry;
}

// Kernel 4: scan bucket totals -> bucket region starts (1563 entries,
// 2 elements per thread over a 2048-wide Hillis-Steele scan).
__global__ __launch_bounds__(1024) void k_scan2(const int* __restrict__ btot,
                                                int* __restrict__ bstart) {
    __shared__ int sm[2048];
    int t = threadIdx.x;
    int i0 = t, i1 = t + 1024;
    int v0 = (i0 < NBUCK) ? btot[i0] : 0;
    int v1 = (i1 < NBUCK) ? btot[i1] : 0;
    sm[i0] = v0; sm[i1] = v1;
    __syncthreads();
    for (int d = 1; d < 2048; d <<= 1) {
        int a0 = (i0 >= d) ? sm[i0 - d] : 0;
        int a1 = (i1 >= d) ? sm[i1 - d] : 0;
        __syncthreads();
        sm[i0] += a0; sm[i1] += a1;
        __syncthreads();
    }
    if (i0 < NBUCK) bstart[i0] = sm[i0] - v0;
    if (i1 < NBUCK) bstart[i1] = sm[i1] - v1;
    if (t == 0) bstart[NBUCK] = sm[2047];   // = N_EDGES
}

// ---------------------------------------------------------------------------
// Kernel 5: scatter edges into bucket regions (LDS cursors, no global atomics)
// Record: src (17 bits) | dst_local (6 bits) << 17. Chunk map = XCD-grouped.
__global__ __launch_bounds__(256) void k_scatter2(const int* __restrict__ ei,
                                                  const int* __restrict__ hist_g,
                                                  const int* __restrict__ bstart,
                                                  unsigned* __restrict__ packed) {
    __shared__ int cur[NBUCK];
    int chunk = chunk_of_block(blockIdx.x);
    const int* hrow = hist_g + (size_t)chunk * NBUCK;
    for (int i = threadIdx.x; i < NBUCK; i += 256) cur[i] = bstart[i] + hrow[i];
    __syncthreads();
    size_t e0 = (size_t)chunk * EPB;
    const int4* sp = (const int4*)(ei + e0);
    const int4* dp = (const int4*)(ei + N_EDGES + e0);
    for (int i = threadIdx.x; i < EPB / 4; i += 256) {
        int4 s = sp[i];
        int4 d = dp[i];
        int p0 = atomicAdd(&cur[d.x >> BSH], 1);
        int p1 = atomicAdd(&cur[d.y >> BSH], 1);
        int p2 = atomicAdd(&cur[d.z >> BSH], 1);
        int p3 = atomicAdd(&cur[d.w >> BSH], 1);
        packed[p0] = (unsigned)s.x | ((unsigned)(d.x & DLM) << 17);
        packed[p1] = (unsigned)s.y | ((unsigned)(d.y & DLM) << 17);
        packed[p2] = (unsigned)s.z | ((unsigned)(d.z & DLM) << 17);
        packed[p3] = (unsigned)s.w | ((unsigned)(d.w & DLM) << 17);
    }
}

// ---------------------------------------------------------------------------
// Kernel 6 (fused sort+agg): one block per 64-dst bucket; packed read once
// into registers, LDS counting-sort, then 4-threads-per-dst aggregation
// with quad shuffle-reduce and fused epilogue.
__global__ __launch_bounds__(256) void k_aggsort(
        const unsigned* __restrict__ packed, const int* __restrict__ bstart,
        const float* __restrict__ el, const float* __restrict__ er,
        const unsigned short* __restrict__ featb, const float* __restrict__ res,
        const float* __restrict__ bias, float* __restrict__ out) {
    __shared__ int cnt[BUCK_W];
    __shared__ int off[BUCK_W];
    __shared__ unsigned srt[SORT_CAP];
    int b = blockIdx.x, t = threadIdx.x;
    int lo = bstart[b], hi = bstart[b + 1];

    if (t < BUCK_W) cnt[t] = 0;
    __syncthreads();

    unsigned pe[RCAP];
    int      tk[RCAP];
    #pragma unroll
    for (int i = 0; i < RCAP; i++) {
        int j = lo + i * 256 + t;
        if (j < hi) {
            unsigned p = packed[j];
            pe[i] = p;
            tk[i] = atomicAdd(&cnt[p >> 17], 1);
        } else {
            pe[i] = 0u; tk[i] = -1;
        }
    }
    __syncthreads();

    if (t < BUCK_W) off[t] = cnt[t];
    __syncthreads();
    #pragma unroll
    for (int d = 1; d < BUCK_W; d <<= 1) {
        int v = (t < BUCK_W && t >= d) ? off[t - d] : 0;
        __syncthreads();
        if (t < BUCK_W) off[t] += v;
        __syncthreads();
    }

    #pragma unroll
    for (int i = 0; i < RCAP; i++) {
        if (tk[i] >= 0) {
            int dl = (int)(pe[i] >> 17);
            srt[off[dl] - cnt[dl] + tk[i]] = pe[i] & 0x1FFFFu;
        }
    }
    __syncthreads();

    // Agg: 4 threads per dst (t = dl*4 + r)
    int dl = t >> 2, r = t & 3;
    int n = b * BUCK_W + dl;
    if (n >= N_NODES) return;
    int sBeg = off[dl] - cnt[dl];
    int sEnd = off[dl];
    float2 ern = *(const float2*)(er + n * 2);
    float den0 = 0.f, den1 = 0.f;
    float S[FH];
    #pragma unroll
    for (int k = 0; k < FH; k++) S[k] = 0.f;

    int j = sBeg + r;
    for (; j + TPD < sEnd; j += 2 * TPD) {
        int sa = (int)srt[j], sb2 = (int)srt[j + TPD];
        float2 ea = *(const float2*)(el + sa * 2);
        float2 eb = *(const float2*)(el + sb2 * 2);
        const uint4* fpa = (const uint4*)(featb + (size_t)sa * FH);
        const uint4* fpb = (const uint4*)(featb + (size_t)sb2 * FH);
        uint4 ua0 = fpa[0], ua1 = fpa[1];
        uint4 ub0 = fpb[0], ub1 = fpb[1];
        float va0 = ea.x + ern.x, va1 = ea.y + ern.y;
        float vb0 = eb.x + ern.x, vb1 = eb.y + ern.y;
        va0 = va0 >= 0.f ? va0 : NEG_SLOPE * va0;
        va1 = va1 >= 0.f ? va1 : NEG_SLOPE * va1;
        vb0 = vb0 >= 0.f ? vb0 : NEG_SLOPE * vb0;
        vb1 = vb1 >= 0.f ? vb1 : NEG_SLOPE * vb1;
        float wa0 = __expf(va0), wa1 = __expf(va1);
        float wb0 = __expf(vb0), wb1 = __expf(vb1);
        den0 += wa0 + wb0; den1 += wa1 + wb1;
        S[0]  = fmaf(wa0, bflo(ua0.x), fmaf(wb0, bflo(ub0.x), S[0]));
        S[1]  = fmaf(wa0, bfhi(ua0.x), fmaf(wb0, bfhi(ub0.x), S[1]));
        S[2]  = fmaf(wa0, bflo(ua0.y), fmaf(wb0, bflo(ub0.y), S[2]));
        S[3]  = fmaf(wa0, bfhi(ua0.y), fmaf(wb0, bfhi(ub0.y), S[3]));
        S[4]  = fmaf(wa0, bflo(ua0.z), fmaf(wb0, bflo(ub0.z), S[4]));
        S[5]  = fmaf(wa0, bfhi(ua0.z), fmaf(wb0, bfhi(ub0.z), S[5]));
        S[6]  = fmaf(wa0, bflo(ua0.w), fmaf(wb0, bflo(ub0.w), S[6]));
        S[7]  = fmaf(wa0, bfhi(ua0.w), fmaf(wb0, bfhi(ub0.w), S[7]));
        S[8]  = fmaf(wa1, bflo(ua1.x), fmaf(wb1, bflo(ub1.x), S[8]));
        S[9]  = fmaf(wa1, bfhi(ua1.x), fmaf(wb1, bfhi(ub1.x), S[9]));
        S[10] = fmaf(wa1, bflo(ua1.y), fmaf(wb1, bflo(ub1.y), S[10]));
        S[11] = fmaf(wa1, bfhi(ua1.y), fmaf(wb1, bfhi(ub1.y), S[11]));
        S[12] = fmaf(wa1, bflo(ua1.z), fmaf(wb1, bflo(ub1.z), S[12]));
        S[13] = fmaf(wa1, bfhi(ua1.z), fmaf(wb1, bfhi(ub1.z), S[13]));
        S[14] = fmaf(wa1, bflo(ua1.w), fmaf(wb1, bflo(ub1.w), S[14]));
        S[15] = fmaf(wa1, bfhi(ua1.w), fmaf(wb1, bfhi(ub1.w), S[15]));
    }
    for (; j < sEnd; j += TPD) {
        int sa = (int)srt[j];
        float2 ea = *(const float2*)(el + sa * 2);
        float v0 = ea.x + ern.x, v1 = ea.y + ern.y;
        v0 = v0 >= 0.f ? v0 : NEG_SLOPE * v0;
        v1 = v1 >= 0.f ? v1 : NEG_SLOPE * v1;
        float w0 = __expf(v0), w1 = __expf(v1);
        den0 += w0; den1 += w1;
        const uint4* fp = (const uint4*)(featb + (size_t)sa * FH);
        uint4 u0 = fp[0], u1 = fp[1];
        S[0]  = fmaf(w0, bflo(u0.x), S[0]);  S[1]  = fmaf(w0, bfhi(u0.x), S[1]);
        S[2]  = fmaf(w0, bflo(u0.y), S[2]);  S[3]  = fmaf(w0, bfhi(u0.y), S[3]);
        S[4]  = fmaf(w0, bflo(u0.z), S[4]);  S[5]  = fmaf(w0, bfhi(u0.z), S[5]);
        S[6]  = fmaf(w0, bflo(u0.w), S[6]);  S[7]  = fmaf(w0, bfhi(u0.w), S[7]);
        S[8]  = fmaf(w1, bflo(u1.x), S[8]);  S[9]  = fmaf(w1, bfhi(u1.x), S[9]);
        S[10] = fmaf(w1, bflo(u1.y), S[10]); S[11] = fmaf(w1, bfhi(u1.y), S[11]);
        S[12] = fmaf(w1, bflo(u1.z), S[12]); S[13] = fmaf(w1, bfhi(u1.z), S[13]);
        S[14] = fmaf(w1, bflo(u1.w), S[14]); S[15] = fmaf(w1, bfhi(u1.w), S[15]);
    }

    // quad reduction (lanes 4k..4k+3 share one dst)
    #pragma unroll
    for (int k = 0; k < FH; k++) {
        S[k] += __shfl_xor(S[k], 1);
        S[k] += __shfl_xor(S[k], 2);
    }
    den0 += __shfl_xor(den0, 1); den0 += __shfl_xor(den0, 2);
    den1 += __shfl_xor(den1, 1); den1 += __shfl_xor(den1, 2);

    if (r == 0) {
        float inv0 = 1.f / fmaxf(den0, EPSF);
        float inv1 = 1.f / fmaxf(den1, EPSF);
        const float* rr = res + (size_t)n * FH;
        float4 r0a = *(const float4*)(rr + 0),  r0b = *(const float4*)(rr + 4);
        float4 r1a = *(const float4*)(rr + 8),  r1b = *(const float4*)(rr + 12);
        float4 oa, ob;
        oa.x = 0.5f * ((S[0] * inv0 + r0a.x + bias[0])  + (S[8]  * inv1 + r1a.x + bias[8]));
        oa.y = 0.5f * ((S[1] * inv0 + r0a.y + bias[1])  + (S[9]  * inv1 + r1a.y + bias[9]));
        oa.z = 0.5f * ((S[2] * inv0 + r0a.z + bias[2])  + (S[10] * inv1 + r1a.z + bias[10]));
        oa.w = 0.5f * ((S[3] * inv0 + r0a.w + bias[3])  + (S[11] * inv1 + r1a.w + bias[11]));
        ob.x = 0.5f * ((S[4] * inv0 + r0b.x + bias[4])  + (S[12] * inv1 + r1b.x + bias[12]));
        ob.y = 0.5f * ((S[5] * inv0 + r0b.y + bias[5])  + (S[13] * inv1 + r1b.y + bias[13]));
        ob.z = 0.5f * ((S[6] * inv0 + r0b.z + bias[6])  + (S[14] * inv1 + r1b.z + bias[14]));
        ob.w = 0.5f * ((S[7] * inv0 + r0b.w + bias[7])  + (S[15] * inv1 + r1b.w + bias[15]));
        *(float4*)(out + (size_t)n * NC + 0) = oa;
        *(float4*)(out + (size_t)n * NC + 4) = ob;
    }
}

extern "C" void kernel_launch(void* const* d_in, const int* in_sizes, int n_in,
                              void* d_out, int out_size, void* d_ws, size_t ws_size,
                              hipStream_t stream) {
    const float* x      = (const float*)d_in[0];
    const int*   ei     = (const int*)d_in[1];
    const float* W      = (const float*)d_in[2];
    const float* attn_l = (const float*)d_in[3];
    const float* attn_r = (const float*)d_in[4];
    const float* bias   = (const float*)d_in[5];
    const float* Wres   = (const float*)d_in[6];
    float* out = (float*)d_out;

    char* ws = (char*)d_ws;
    const size_t szFB   = (size_t)N_NODES * FH * sizeof(unsigned short); // 3.2 MB
    const size_t szNF   = (size_t)N_NODES * FH * sizeof(float);          // 6.4 MB
    const size_t szNH   = (size_t)N_NODES * HEADS * sizeof(float);       // 0.8 MB
    const size_t szHist = (((size_t)B1 * NBUCK * sizeof(int)) + 255) & ~(size_t)255;
    const size_t szBt   = 8192;
    size_t off = 0;
    unsigned short* featb = (unsigned short*)(ws + off); off += szFB;
    float*    res    = (float*)(ws + off); off += szNF;
    float*    el     = (float*)(ws + off); off += szNH;
    float*    er     = (float*)(ws + off); off += szNH;
    int*      hist_g = (int*)  (ws + off); off += szHist;
    int*      btot   = (int*)  (ws + off); off += szBt;
    int*      bstart = (int*)  (ws + off); off += szBt;
    unsigned* packed = (unsigned*)(ws + off); off += (size_t)N_EDGES * sizeof(unsigned);

    k_node<<<(N_NODES / 16 + 3) / 4, 256, 0, stream>>>(x, W, Wres, attn_l, attn_r,
                                                       featb, res, el, er);
    k_count<<<B1, 256, 0, stream>>>(ei, hist_g);
    k_scan1<<<NBUCK, 64, 0, stream>>>(hist_g, btot);
    k_scan2<<<1, 1024, 0, stream>>>(btot, bstart);
    k_scatter2<<<B1, 256, 0, stream>>>(ei, hist_g, bstart, packed);
    k_aggsort<<<NBUCK, 256, 0, stream>>>(packed, bstart, el, er, featb, res, bias, out);
}

// Round 14
// 112.228 us; speedup vs baseline: 1.0733x; 1.0733x over previous
//
#include <hip/hip_runtime.h>
#include <math.h>

#define N_NODES 100000
#define N_EDGES 3200000
#define IN_FEAT 256
#define HEADS 2
#define NC 8
#define FH 16               // HEADS*NC
#define NEG_SLOPE 0.2f
#define EPSF 1e-15f

// Bucketed partition: 64 dsts per bucket.
#define BSH 6
#define BUCK_W 64
#define DLM 63
#define NBUCK ((N_NODES + BUCK_W - 1) / BUCK_W)   // 1563
#define B1 256                                    // partition chunks (8 XCDs x 32)
#define EPB (N_EDGES / B1)                        // 12500 edges/chunk (exact)

// Fused sort+agg: LDS capacity per bucket (mean 2048, sd 45; +11 sd margin).
#define SORT_CAP 2560
#define RCAP (SORT_CAP / 256)    // 10 register-cached records per thread
#define TPD 4                    // threads per dst in agg phase

typedef float f32x4 __attribute__((ext_vector_type(4)));
typedef short bf16x8 __attribute__((ext_vector_type(8)));

__device__ __forceinline__ unsigned short f2bf(float f) {
    unsigned u = __float_as_uint(f);
    u += 0x7FFFu + ((u >> 16) & 1u);      // round-to-nearest-even
    return (unsigned short)(u >> 16);
}
__device__ __forceinline__ float bflo(unsigned u) { return __uint_as_float(u << 16); }
__device__ __forceinline__ float bfhi(unsigned u) { return __uint_as_float(u & 0xFFFF0000u); }

// XCD-grouped bijective chunk map (8 XCDs x 32 chunks): each XCD owns a
// contiguous chunk range -> its packed-runs in every bucket segment are
// contiguous and L2-local (no cross-XCD dirty-line sharing).
__device__ __forceinline__ int chunk_of_block(int bid) {
    return (bid & 7) * (B1 / 8) + (bid >> 3);
}

// ---------------------------------------------------------------------------
// Kernel 1 (MFMA node transform + FUSED histogram): 1563 blocks.
// All blocks: one wave per 16 nodes; D[16x32] = bf16(x)@bf16([W|Wres]).
// Blocks 0..B1-1 additionally histogram their edge chunk (independent data;
// hides k_count's 1-block/CU latency inside the node kernel's schedule).
__global__ __launch_bounds__(256) void k_node(
        const float* __restrict__ x, const float* __restrict__ W,
        const float* __restrict__ Wres, const float* __restrict__ attn_l,
        const float* __restrict__ attn_r, const int* __restrict__ ei,
        unsigned short* __restrict__ featb, float* __restrict__ res,
        float* __restrict__ el, float* __restrict__ er,
        int* __restrict__ hist_g) {
    __shared__ int h[NBUCK];
    int t = threadIdx.x;
    bool do_count = (blockIdx.x < B1);
    if (do_count) {
        for (int i = t; i < NBUCK; i += 256) h[i] = 0;
    }

    // ---- node phase (wave-granular guard; no returns, shuffles wave-uniform)
    int wid = (blockIdx.x * 256 + t) >> 6;
    int n0 = wid * 16;
    if (n0 < N_NODES) {
        int l   = t & 63;
        int col = l & 15;
        int g   = l >> 4;

        bf16x8 bw[8], bq[8];
        #pragma unroll
        for (int kk = 0; kk < 8; kk++) {
            #pragma unroll
            for (int j = 0; j < 8; j++) {
                int k = kk * 32 + g * 8 + j;
                bw[kk][j] = (short)f2bf(W[k * FH + col]);
                bq[kk][j] = (short)f2bf(Wres[k * FH + col]);
            }
        }

        const float* xr = x + (size_t)(n0 + col) * IN_FEAT;
        f32x4 acc0 = {0.f, 0.f, 0.f, 0.f};
        f32x4 acc1 = {0.f, 0.f, 0.f, 0.f};
        float ss = 0.f;
        #pragma unroll
        for (int kk = 0; kk < 8; kk++) {
            float4 v0 = *(const float4*)(xr + kk * 32 + g * 8);
            float4 v1 = *(const float4*)(xr + kk * 32 + g * 8 + 4);
            ss += v0.x * v0.x + v0.y * v0.y + v0.z * v0.z + v0.w * v0.w
                + v1.x * v1.x + v1.y * v1.y + v1.z * v1.z + v1.w * v1.w;
            bf16x8 a;
            a[0] = (short)f2bf(v0.x); a[1] = (short)f2bf(v0.y);
            a[2] = (short)f2bf(v0.z); a[3] = (short)f2bf(v0.w);
            a[4] = (short)f2bf(v1.x); a[5] = (short)f2bf(v1.y);
            a[6] = (short)f2bf(v1.z); a[7] = (short)f2bf(v1.w);
            acc0 = __builtin_amdgcn_mfma_f32_16x16x32_bf16(a, bw[kk], acc0, 0, 0, 0);
            acc1 = __builtin_amdgcn_mfma_f32_16x16x32_bf16(a, bq[kk], acc1, 0, 0, 0);
        }

        ss += __shfl_xor(ss, 16);
        ss += __shfl_xor(ss, 32);
        float norm = fmaxf(sqrtf(ss), EPSF);
        float z = fminf(norm, 1.f - 1e-7f);
        float at = 0.5f * (log1pf(z) - log1pf(-z));   // artanh(clip)
        float scale = at / norm;

        float alc = attn_l[col], arc = attn_r[col];

        #pragma unroll
        for (int i = 0; i < 4; i++) {
            int ri = g * 4 + i;
            float s_i = __shfl(scale, ri);
            int nr = n0 + ri;
            float f_i = acc0[i] * s_i;
            float q_i = acc1[i] * s_i;
            featb[(size_t)nr * FH + col] = f2bf(f_i);
            res  [(size_t)nr * FH + col] = q_i;
            float pl = f_i * alc, pr = f_i * arc;
            float pl0 = (col < 8) ? pl : 0.f, pl1 = (col < 8) ? 0.f : pl;
            float pr0 = (col < 8) ? pr : 0.f, pr1 = (col < 8) ? 0.f : pr;
            #pragma unroll
            for (int m = 1; m < 16; m <<= 1) {
                pl0 += __shfl_xor(pl0, m); pl1 += __shfl_xor(pl1, m);
                pr0 += __shfl_xor(pr0, m); pr1 += __shfl_xor(pr1, m);
            }
            if (col == 0) {
                *(float2*)(el + nr * 2) = make_float2(pl0, pl1);
                *(float2*)(er + nr * 2) = make_float2(pr0, pr1);
            }
        }
    }

    // ---- count phase (blocks 0..B1-1 only; all threads alive)
    if (do_count) {
        __syncthreads();                    // h[] zeroing complete
        int chunk = chunk_of_block(blockIdx.x);
        const int4* dp = (const int4*)(ei + N_EDGES + (size_t)chunk * EPB);
        for (int i = t; i < EPB / 4; i += 256) {
            int4 d = dp[i];
            atomicAdd(&h[d.x >> BSH], 1);
            atomicAdd(&h[d.y >> BSH], 1);
            atomicAdd(&h[d.z >> BSH], 1);
            atomicAdd(&h[d.w >> BSH], 1);
        }
        __syncthreads();
        int* outp = hist_g + (size_t)chunk * NBUCK;
        for (int i = t; i < NBUCK; i += 256) outp[i] = h[i];
    }
}

// ---------------------------------------------------------------------------
// Kernel 2: per-bucket exclusive scan over the B1 chunks (in place) + totals.
__global__ __launch_bounds__(64) void k_scan1(int* __restrict__ hist_g,
                                              int* __restrict__ btot) {
    __shared__ int sm[64];
    int bucket = blockIdx.x;
    int t = threadIdx.x;
    int carry = 0;
    for (int base = 0; base < B1; base += 64) {
        int blk = base + t;
        int v = hist_g[(size_t)blk * NBUCK + bucket];       // B1 % 64 == 0
        __syncthreads();
        sm[t] = v;
        __syncthreads();
        for (int off = 1; off < 64; off <<= 1) {
            int u = (t >= off) ? sm[t - off] : 0;
            __syncthreads();
            sm[t] += u;
            __syncthreads();
        }
        hist_g[(size_t)blk * NBUCK + bucket] = carry + sm[t] - v;
        carry += sm[63];
    }
    if (t == 0) btot[bucket] = carry;
}

// Kernel 3: scan bucket totals -> bucket region starts (1563 entries,
// 2 elements per thread over a 2048-wide Hillis-Steele scan).
__global__ __launch_bounds__(1024) void k_scan2(const int* __restrict__ btot,
                                                int* __restrict__ bstart) {
    __shared__ int sm[2048];
    int t = threadIdx.x;
    int i0 = t, i1 = t + 1024;
    int v0 = (i0 < NBUCK) ? btot[i0] : 0;
    int v1 = (i1 < NBUCK) ? btot[i1] : 0;
    sm[i0] = v0; sm[i1] = v1;
    __syncthreads();
    for (int d = 1; d < 2048; d <<= 1) {
        int a0 = (i0 >= d) ? sm[i0 - d] : 0;
        int a1 = (i1 >= d) ? sm[i1 - d] : 0;
        __syncthreads();
        sm[i0] += a0; sm[i1] += a1;
        __syncthreads();
    }
    if (i0 < NBUCK) bstart[i0] = sm[i0] - v0;
    if (i1 < NBUCK) bstart[i1] = sm[i1] - v1;
    if (t == 0) bstart[NBUCK] = sm[2047];   // = N_EDGES
}

// ---------------------------------------------------------------------------
// Kernel 4: scatter edges into bucket regions (LDS cursors, no global atomics)
// Record: src (17 bits) | dst_local (6 bits) << 17. Chunk map = XCD-grouped.
__global__ __launch_bounds__(256) void k_scatter2(const int* __restrict__ ei,
                                                  const int* __restrict__ hist_g,
                                                  const int* __restrict__ bstart,
                                                  unsigned* __restrict__ packed) {
    __shared__ int cur[NBUCK];
    int chunk = chunk_of_block(blockIdx.x);
    const int* hrow = hist_g + (size_t)chunk * NBUCK;
    for (int i = threadIdx.x; i < NBUCK; i += 256) cur[i] = bstart[i] + hrow[i];
    __syncthreads();
    size_t e0 = (size_t)chunk * EPB;
    const int4* sp = (const int4*)(ei + e0);
    const int4* dp = (const int4*)(ei + N_EDGES + e0);
    for (int i = threadIdx.x; i < EPB / 4; i += 256) {
        int4 s = sp[i];
        int4 d = dp[i];
        int p0 = atomicAdd(&cur[d.x >> BSH], 1);
        int p1 = atomicAdd(&cur[d.y >> BSH], 1);
        int p2 = atomicAdd(&cur[d.z >> BSH], 1);
        int p3 = atomicAdd(&cur[d.w >> BSH], 1);
        packed[p0] = (unsigned)s.x | ((unsigned)(d.x & DLM) << 17);
        packed[p1] = (unsigned)s.y | ((unsigned)(d.y & DLM) << 17);
        packed[p2] = (unsigned)s.z | ((unsigned)(d.z & DLM) << 17);
        packed[p3] = (unsigned)s.w | ((unsigned)(d.w & DLM) << 17);
    }
}

// ---------------------------------------------------------------------------
// Kernel 5 (fused sort+agg): one block per 64-dst bucket; packed read once
// into registers, LDS counting-sort, then 4-threads-per-dst aggregation
// with UNROLL-4 gather batching (4 featb gathers in flight) and fused epilogue.
__global__ __launch_bounds__(256) void k_aggsort(
        const unsigned* __restrict__ packed, const int* __restrict__ bstart,
        const float* __restrict__ el, const float* __restrict__ er,
        const unsigned short* __restrict__ featb, const float* __restrict__ res,
        const float* __restrict__ bias, float* __restrict__ out) {
    __shared__ int cnt[BUCK_W];
    __shared__ int off[BUCK_W];
    __shared__ unsigned srt[SORT_CAP];
    int b = blockIdx.x, t = threadIdx.x;
    int lo = bstart[b], hi = bstart[b + 1];

    if (t < BUCK_W) cnt[t] = 0;
    __syncthreads();

    unsigned pe[RCAP];
    int      tk[RCAP];
    #pragma unroll
    for (int i = 0; i < RCAP; i++) {
        int j = lo + i * 256 + t;
        if (j < hi) {
            unsigned p = packed[j];
            pe[i] = p;
            tk[i] = atomicAdd(&cnt[p >> 17], 1);
        } else {
            pe[i] = 0u; tk[i] = -1;
        }
    }
    __syncthreads();

    if (t < BUCK_W) off[t] = cnt[t];
    __syncthreads();
    #pragma unroll
    for (int d = 1; d < BUCK_W; d <<= 1) {
        int v = (t < BUCK_W && t >= d) ? off[t - d] : 0;
        __syncthreads();
        if (t < BUCK_W) off[t] += v;
        __syncthreads();
    }

    #pragma unroll
    for (int i = 0; i < RCAP; i++) {
        if (tk[i] >= 0) {
            int dl = (int)(pe[i] >> 17);
            srt[off[dl] - cnt[dl] + tk[i]] = pe[i] & 0x1FFFFu;
        }
    }
    __syncthreads();

    // Agg: 4 threads per dst (t = dl*4 + r)
    int dl = t >> 2, r = t & 3;
    int n = b * BUCK_W + dl;
    if (n >= N_NODES) return;
    int sBeg = off[dl] - cnt[dl];
    int sEnd = off[dl];
    float2 ern = *(const float2*)(er + n * 2);
    float den0 = 0.f, den1 = 0.f;
    float S[FH];
    #pragma unroll
    for (int k = 0; k < FH; k++) S[k] = 0.f;

    int j = sBeg + r;
    // unroll-4: batch all loads first (4 el + 8 uint4 in flight), then compute
    for (; j + 3 * TPD < sEnd; j += 4 * TPD) {
        int s0 = (int)srt[j];
        int s1 = (int)srt[j + TPD];
        int s2 = (int)srt[j + 2 * TPD];
        int s3 = (int)srt[j + 3 * TPD];
        float2 e0 = *(const float2*)(el + s0 * 2);
        float2 e1 = *(const float2*)(el + s1 * 2);
        float2 e2 = *(const float2*)(el + s2 * 2);
        float2 e3 = *(const float2*)(el + s3 * 2);
        const uint4* f0p = (const uint4*)(featb + (size_t)s0 * FH);
        const uint4* f1p = (const uint4*)(featb + (size_t)s1 * FH);
        const uint4* f2p = (const uint4*)(featb + (size_t)s2 * FH);
        const uint4* f3p = (const uint4*)(featb + (size_t)s3 * FH);
        uint4 u00 = f0p[0], u01 = f0p[1];
        uint4 u10 = f1p[0], u11 = f1p[1];
        uint4 u20 = f2p[0], u21 = f2p[1];
        uint4 u30 = f3p[0], u31 = f3p[1];
        float a0 = e0.x + ern.x, b0 = e0.y + ern.y;
        float a1 = e1.x + ern.x, b1 = e1.y + ern.y;
        float a2 = e2.x + ern.x, b2 = e2.y + ern.y;
        float a3 = e3.x + ern.x, b3 = e3.y + ern.y;
        a0 = a0 >= 0.f ? a0 : NEG_SLOPE * a0;  b0 = b0 >= 0.f ? b0 : NEG_SLOPE * b0;
        a1 = a1 >= 0.f ? a1 : NEG_SLOPE * a1;  b1 = b1 >= 0.f ? b1 : NEG_SLOPE * b1;
        a2 = a2 >= 0.f ? a2 : NEG_SLOPE * a2;  b2 = b2 >= 0.f ? b2 : NEG_SLOPE * b2;
        a3 = a3 >= 0.f ? a3 : NEG_SLOPE * a3;  b3 = b3 >= 0.f ? b3 : NEG_SLOPE * b3;
        float w00 = __expf(a0), w01 = __expf(b0);
        float w10 = __expf(a1), w11 = __expf(b1);
        float w20 = __expf(a2), w21 = __expf(b2);
        float w30 = __expf(a3), w31 = __expf(b3);
        den0 += w00 + w10 + w20 + w30;
        den1 += w01 + w11 + w21 + w31;
        S[0]  = fmaf(w00, bflo(u00.x), fmaf(w10, bflo(u10.x), fmaf(w20, bflo(u20.x), fmaf(w30, bflo(u30.x), S[0]))));
        S[1]  = fmaf(w00, bfhi(u00.x), fmaf(w10, bfhi(u10.x), fmaf(w20, bfhi(u20.x), fmaf(w30, bfhi(u30.x), S[1]))));
        S[2]  = fmaf(w00, bflo(u00.y), fmaf(w10, bflo(u10.y), fmaf(w20, bflo(u20.y), fmaf(w30, bflo(u30.y), S[2]))));
        S[3]  = fmaf(w00, bfhi(u00.y), fmaf(w10, bfhi(u10.y), fmaf(w20, bfhi(u20.y), fmaf(w30, bfhi(u30.y), S[3]))));
        S[4]  = fmaf(w00, bflo(u00.z), fmaf(w10, bflo(u10.z), fmaf(w20, bflo(u20.z), fmaf(w30, bflo(u30.z), S[4]))));
        S[5]  = fmaf(w00, bfhi(u00.z), fmaf(w10, bfhi(u10.z), fmaf(w20, bfhi(u20.z), fmaf(w30, bfhi(u30.z), S[5]))));
        S[6]  = fmaf(w00, bflo(u00.w), fmaf(w10, bflo(u10.w), fmaf(w20, bflo(u20.w), fmaf(w30, bflo(u30.w), S[6]))));
        S[7]  = fmaf(w00, bfhi(u00.w), fmaf(w10, bfhi(u10.w), fmaf(w20, bfhi(u20.w), fmaf(w30, bfhi(u30.w), S[7]))));
        S[8]  = fmaf(w01, bflo(u01.x), fmaf(w11, bflo(u11.x), fmaf(w21, bflo(u21.x), fmaf(w31, bflo(u31.x), S[8]))));
        S[9]  = fmaf(w01, bfhi(u01.x), fmaf(w11, bfhi(u11.x), fmaf(w21, bfhi(u21.x), fmaf(w31, bfhi(u31.x), S[9]))));
        S[10] = fmaf(w01, bflo(u01.y), fmaf(w11, bflo(u11.y), fmaf(w21, bflo(u21.y), fmaf(w31, bflo(u31.y), S[10]))));
        S[11] = fmaf(w01, bfhi(u01.y), fmaf(w11, bfhi(u11.y), fmaf(w21, bfhi(u21.y), fmaf(w31, bfhi(u31.y), S[11]))));
        S[12] = fmaf(w01, bflo(u01.z), fmaf(w11, bflo(u11.z), fmaf(w21, bflo(u21.z), fmaf(w31, bflo(u31.z), S[12]))));
        S[13] = fmaf(w01, bfhi(u01.z), fmaf(w11, bfhi(u11.z), fmaf(w21, bfhi(u21.z), fmaf(w31, bfhi(u31.z), S[13]))));
        S[14] = fmaf(w01, bflo(u01.w), fmaf(w11, bflo(u11.w), fmaf(w21, bflo(u21.w), fmaf(w31, bflo(u31.w), S[14]))));
        S[15] = fmaf(w01, bfhi(u01.w), fmaf(w11, bfhi(u11.w), fmaf(w21, bfhi(u21.w), fmaf(w31, bfhi(u31.w), S[15]))));
    }
    for (; j < sEnd; j += TPD) {
        int sa = (int)srt[j];
        float2 ea = *(const float2*)(el + sa * 2);
        float v0 = ea.x + ern.x, v1 = ea.y + ern.y;
        v0 = v0 >= 0.f ? v0 : NEG_SLOPE * v0;
        v1 = v1 >= 0.f ? v1 : NEG_SLOPE * v1;
        float w0 = __expf(v0), w1 = __expf(v1);
        den0 += w0; den1 += w1;
        const uint4* fp = (const uint4*)(featb + (size_t)sa * FH);
        uint4 u0 = fp[0], u1 = fp[1];
        S[0]  = fmaf(w0, bflo(u0.x), S[0]);  S[1]  = fmaf(w0, bfhi(u0.x), S[1]);
        S[2]  = fmaf(w0, bflo(u0.y), S[2]);  S[3]  = fmaf(w0, bfhi(u0.y), S[3]);
        S[4]  = fmaf(w0, bflo(u0.z), S[4]);  S[5]  = fmaf(w0, bfhi(u0.z), S[5]);
        S[6]  = fmaf(w0, bflo(u0.w), S[6]);  S[7]  = fmaf(w0, bfhi(u0.w), S[7]);
        S[8]  = fmaf(w1, bflo(u1.x), S[8]);  S[9]  = fmaf(w1, bfhi(u1.x), S[9]);
        S[10] = fmaf(w1, bflo(u1.y), S[10]); S[11] = fmaf(w1, bfhi(u1.y), S[11]);
        S[12] = fmaf(w1, bflo(u1.z), S[12]); S[13] = fmaf(w1, bfhi(u1.z), S[13]);
        S[14] = fmaf(w1, bflo(u1.w), S[14]); S[15] = fmaf(w1, bfhi(u1.w), S[15]);
    }

    // quad reduction (lanes 4k..4k+3 share one dst)
    #pragma unroll
    for (int k = 0; k < FH; k++) {
        S[k] += __shfl_xor(S[k], 1);
        S[k] += __shfl_xor(S[k], 2);
    }
    den0 += __shfl_xor(den0, 1); den0 += __shfl_xor(den0, 2);
    den1 += __shfl_xor(den1, 1); den1 += __shfl_xor(den1, 2);

    if (r == 0) {
        float inv0 = 1.f / fmaxf(den0, EPSF);
        float inv1 = 1.f / fmaxf(den1, EPSF);
        const float* rr = res + (size_t)n * FH;
        float4 r0a = *(const float4*)(rr + 0),  r0b = *(const float4*)(rr + 4);
        float4 r1a = *(const float4*)(rr + 8),  r1b = *(const float4*)(rr + 12);
        float4 oa, ob;
        oa.x = 0.5f * ((S[0] * inv0 + r0a.x + bias[0])  + (S[8]  * inv1 + r1a.x + bias[8]));
        oa.y = 0.5f * ((S[1] * inv0 + r0a.y + bias[1])  + (S[9]  * inv1 + r1a.y + bias[9]));
        oa.z = 0.5f * ((S[2] * inv0 + r0a.z + bias[2])  + (S[10] * inv1 + r1a.z + bias[10]));
        oa.w = 0.5f * ((S[3] * inv0 + r0a.w + bias[3])  + (S[11] * inv1 + r1a.w + bias[11]));
        ob.x = 0.5f * ((S[4] * inv0 + r0b.x + bias[4])  + (S[12] * inv1 + r1b.x + bias[12]));
        ob.y = 0.5f * ((S[5] * inv0 + r0b.y + bias[5])  + (S[13] * inv1 + r1b.y + bias[13]));
        ob.z = 0.5f * ((S[6] * inv0 + r0b.z + bias[6])  + (S[14] * inv1 + r1b.z + bias[14]));
        ob.w = 0.5f * ((S[7] * inv0 + r0b.w + bias[7])  + (S[15] * inv1 + r1b.w + bias[15]));
        *(float4*)(out + (size_t)n * NC + 0) = oa;
        *(float4*)(out + (size_t)n * NC + 4) = ob;
    }
}

extern "C" void kernel_launch(void* const* d_in, const int* in_sizes, int n_in,
                              void* d_out, int out_size, void* d_ws, size_t ws_size,
                              hipStream_t stream) {
    const float* x      = (const float*)d_in[0];
    const int*   ei     = (const int*)d_in[1];
    const float* W      = (const float*)d_in[2];
    const float* attn_l = (const float*)d_in[3];
    const float* attn_r = (const float*)d_in[4];
    const float* bias   = (const float*)d_in[5];
    const float* Wres   = (const float*)d_in[6];
    float* out = (float*)d_out;

    char* ws = (char*)d_ws;
    const size_t szFB   = (size_t)N_NODES * FH * sizeof(unsigned short); // 3.2 MB
    const size_t szNF   = (size_t)N_NODES * FH * sizeof(float);          // 6.4 MB
    const size_t szNH   = (size_t)N_NODES * HEADS * sizeof(float);       // 0.8 MB
    const size_t szHist = (((size_t)B1 * NBUCK * sizeof(int)) + 255) & ~(size_t)255;
    const size_t szBt   = 8192;
    size_t off = 0;
    unsigned short* featb = (unsigned short*)(ws + off); off += szFB;
    float*    res    = (float*)(ws + off); off += szNF;
    float*    el     = (float*)(ws + off); off += szNH;
    float*    er     = (float*)(ws + off); off += szNH;
    int*      hist_g = (int*)  (ws + off); off += szHist;
    int*      btot   = (int*)  (ws + off); off += szBt;
    int*      bstart = (int*)  (ws + off); off += szBt;
    unsigned* packed = (unsigned*)(ws + off); off += (size_t)N_EDGES * sizeof(unsigned);

    // 1563 blocks: node transform everywhere + histogram in blocks 0..255
    k_node<<<(N_NODES / 16 + 3) / 4, 256, 0, stream>>>(x, W, Wres, attn_l, attn_r,
                                                       ei, featb, res, el, er, hist_g);
    k_scan1<<<NBUCK, 64, 0, stream>>>(hist_g, btot);
    k_scan2<<<1, 1024, 0, stream>>>(btot, bstart);
    k_scatter2<<<B1, 256, 0, stream>>>(ei, hist_g, bstart, packed);
    k_aggsort<<<NBUCK, 256, 0, stream>>>(packed, bstart, el, er, featb, res, bias, out);
}

// Round 15
// 109.904 us; speedup vs baseline: 1.0960x; 1.0211x over previous
//
#include <hip/hip_runtime.h>
#include <math.h>

#define N_NODES 100000
#define N_EDGES 3200000
#define IN_FEAT 256
#define HEADS 2
#define NC 8
#define FH 16               // HEADS*NC
#define NEG_SLOPE 0.2f
#define EPSF 1e-15f

// Bucketed partition: 64 dsts per bucket.
#define BSH 6
#define BUCK_W 64
#define DLM 63
#define NBUCK ((N_NODES + BUCK_W - 1) / BUCK_W)   // 1563
#define B1 256                                    // partition chunks (8 XCDs x 32)
#define EPB (N_EDGES / B1)                        // 12500 edges/chunk (exact)

// Fused sort+agg: LDS capacity per bucket (mean 2048, sd 45; +11 sd margin).
#define SORT_CAP 2560
#define RCAP (SORT_CAP / 256)    // 10 register-cached records per thread
#define TPD 4                    // threads per dst in agg phase

typedef float f32x4 __attribute__((ext_vector_type(4)));
typedef short bf16x8 __attribute__((ext_vector_type(8)));

__device__ __forceinline__ unsigned short f2bf(float f) {
    unsigned u = __float_as_uint(f);
    u += 0x7FFFu + ((u >> 16) & 1u);      // round-to-nearest-even
    return (unsigned short)(u >> 16);
}
__device__ __forceinline__ float bflo(unsigned u) { return __uint_as_float(u << 16); }
__device__ __forceinline__ float bfhi(unsigned u) { return __uint_as_float(u & 0xFFFF0000u); }

// XCD-grouped bijective chunk map (8 XCDs x 32 chunks): each XCD owns a
// contiguous chunk range -> its packed-runs in every bucket segment are
// contiguous and L2-local (no cross-XCD dirty-line sharing).
__device__ __forceinline__ int chunk_of_block(int bid) {
    return (bid & 7) * (B1 / 8) + (bid >> 3);
}

// ---------------------------------------------------------------------------
// Kernel 1 (MFMA node transform + FUSED histogram): 1563 blocks.
// All blocks: one wave per 16 nodes; D[16x32] = bf16(x)@bf16([W|Wres]).
// Blocks 0..B1-1 additionally histogram their edge chunk.
__global__ __launch_bounds__(256) void k_node(
        const float* __restrict__ x, const float* __restrict__ W,
        const float* __restrict__ Wres, const float* __restrict__ attn_l,
        const float* __restrict__ attn_r, const int* __restrict__ ei,
        unsigned short* __restrict__ featb, float* __restrict__ res,
        float* __restrict__ el, float* __restrict__ er,
        int* __restrict__ hist_g) {
    __shared__ int h[NBUCK];
    int t = threadIdx.x;
    bool do_count = (blockIdx.x < B1);
    if (do_count) {
        for (int i = t; i < NBUCK; i += 256) h[i] = 0;
    }

    // ---- node phase (wave-granular guard; no returns, shuffles wave-uniform)
    int wid = (blockIdx.x * 256 + t) >> 6;
    int n0 = wid * 16;
    if (n0 < N_NODES) {
        int l   = t & 63;
        int col = l & 15;
        int g   = l >> 4;

        bf16x8 bw[8], bq[8];
        #pragma unroll
        for (int kk = 0; kk < 8; kk++) {
            #pragma unroll
            for (int j = 0; j < 8; j++) {
                int k = kk * 32 + g * 8 + j;
                bw[kk][j] = (short)f2bf(W[k * FH + col]);
                bq[kk][j] = (short)f2bf(Wres[k * FH + col]);
            }
        }

        const float* xr = x + (size_t)(n0 + col) * IN_FEAT;
        f32x4 acc0 = {0.f, 0.f, 0.f, 0.f};
        f32x4 acc1 = {0.f, 0.f, 0.f, 0.f};
        float ss = 0.f;
        #pragma unroll
        for (int kk = 0; kk < 8; kk++) {
            float4 v0 = *(const float4*)(xr + kk * 32 + g * 8);
            float4 v1 = *(const float4*)(xr + kk * 32 + g * 8 + 4);
            ss += v0.x * v0.x + v0.y * v0.y + v0.z * v0.z + v0.w * v0.w
                + v1.x * v1.x + v1.y * v1.y + v1.z * v1.z + v1.w * v1.w;
            bf16x8 a;
            a[0] = (short)f2bf(v0.x); a[1] = (short)f2bf(v0.y);
            a[2] = (short)f2bf(v0.z); a[3] = (short)f2bf(v0.w);
            a[4] = (short)f2bf(v1.x); a[5] = (short)f2bf(v1.y);
            a[6] = (short)f2bf(v1.z); a[7] = (short)f2bf(v1.w);
            acc0 = __builtin_amdgcn_mfma_f32_16x16x32_bf16(a, bw[kk], acc0, 0, 0, 0);
            acc1 = __builtin_amdgcn_mfma_f32_16x16x32_bf16(a, bq[kk], acc1, 0, 0, 0);
        }

        ss += __shfl_xor(ss, 16);
        ss += __shfl_xor(ss, 32);
        float norm = fmaxf(sqrtf(ss), EPSF);
        float z = fminf(norm, 1.f - 1e-7f);
        float at = 0.5f * (log1pf(z) - log1pf(-z));   // artanh(clip)
        float scale = at / norm;

        float alc = attn_l[col], arc = attn_r[col];

        #pragma unroll
        for (int i = 0; i < 4; i++) {
            int ri = g * 4 + i;
            float s_i = __shfl(scale, ri);
            int nr = n0 + ri;
            float f_i = acc0[i] * s_i;
            float q_i = acc1[i] * s_i;
            featb[(size_t)nr * FH + col] = f2bf(f_i);
            res  [(size_t)nr * FH + col] = q_i;
            float pl = f_i * alc, pr = f_i * arc;
            float pl0 = (col < 8) ? pl : 0.f, pl1 = (col < 8) ? 0.f : pl;
            float pr0 = (col < 8) ? pr : 0.f, pr1 = (col < 8) ? 0.f : pr;
            #pragma unroll
            for (int m = 1; m < 16; m <<= 1) {
                pl0 += __shfl_xor(pl0, m); pl1 += __shfl_xor(pl1, m);
                pr0 += __shfl_xor(pr0, m); pr1 += __shfl_xor(pr1, m);
            }
            if (col == 0) {
                *(float2*)(el + nr * 2) = make_float2(pl0, pl1);
                *(float2*)(er + nr * 2) = make_float2(pr0, pr1);
            }
        }
    }

    // ---- count phase (blocks 0..B1-1 only; all threads alive)
    if (do_count) {
        __syncthreads();                    // h[] zeroing complete
        int chunk = chunk_of_block(blockIdx.x);
        const int4* dp = (const int4*)(ei + N_EDGES + (size_t)chunk * EPB);
        for (int i = t; i < EPB / 4; i += 256) {
            int4 d = dp[i];
            atomicAdd(&h[d.x >> BSH], 1);
            atomicAdd(&h[d.y >> BSH], 1);
            atomicAdd(&h[d.z >> BSH], 1);
            atomicAdd(&h[d.w >> BSH], 1);
        }
        __syncthreads();
        int* outp = hist_g + (size_t)chunk * NBUCK;
        for (int i = t; i < NBUCK; i += 256) outp[i] = h[i];
    }
}

// ---------------------------------------------------------------------------
// Kernel 2: per-bucket exclusive scan over the B1 chunks (in place) + totals.
__global__ __launch_bounds__(64) void k_scan1(int* __restrict__ hist_g,
                                              int* __restrict__ btot) {
    __shared__ int sm[64];
    int bucket = blockIdx.x;
    int t = threadIdx.x;
    int carry = 0;
    for (int base = 0; base < B1; base += 64) {
        int blk = base + t;
        int v = hist_g[(size_t)blk * NBUCK + bucket];       // B1 % 64 == 0
        __syncthreads();
        sm[t] = v;
        __syncthreads();
        for (int off = 1; off < 64; off <<= 1) {
            int u = (t >= off) ? sm[t - off] : 0;
            __syncthreads();
            sm[t] += u;
            __syncthreads();
        }
        hist_g[(size_t)blk * NBUCK + bucket] = carry + sm[t] - v;
        carry += sm[63];
    }
    if (t == 0) btot[bucket] = carry;
}

// Kernel 3: scan bucket totals -> bucket region starts (1563 entries,
// 2 elements per thread over a 2048-wide Hillis-Steele scan).
__global__ __launch_bounds__(1024) void k_scan2(const int* __restrict__ btot,
                                                int* __restrict__ bstart) {
    __shared__ int sm[2048];
    int t = threadIdx.x;
    int i0 = t, i1 = t + 1024;
    int v0 = (i0 < NBUCK) ? btot[i0] : 0;
    int v1 = (i1 < NBUCK) ? btot[i1] : 0;
    sm[i0] = v0; sm[i1] = v1;
    __syncthreads();
    for (int d = 1; d < 2048; d <<= 1) {
        int a0 = (i0 >= d) ? sm[i0 - d] : 0;
        int a1 = (i1 >= d) ? sm[i1 - d] : 0;
        __syncthreads();
        sm[i0] += a0; sm[i1] += a1;
        __syncthreads();
    }
    if (i0 < NBUCK) bstart[i0] = sm[i0] - v0;
    if (i1 < NBUCK) bstart[i1] = sm[i1] - v1;
    if (t == 0) bstart[NBUCK] = sm[2047];   // = N_EDGES
}

// ---------------------------------------------------------------------------
// Kernel 4: scatter edges into bucket regions (LDS cursors, no global atomics)
// Record: src (17 bits) | dst_local (6 bits) << 17. Chunk map = XCD-grouped.
// 1024 threads/block: 16 waves/CU (was 4) to hide the cursor-atomic +
// scattered-store latency chain; per-thread work drops to ~3 iterations.
__global__ __launch_bounds__(1024) void k_scatter2(const int* __restrict__ ei,
                                                   const int* __restrict__ hist_g,
                                                   const int* __restrict__ bstart,
                                                   unsigned* __restrict__ packed) {
    __shared__ int cur[NBUCK];
    int chunk = chunk_of_block(blockIdx.x);
    const int* hrow = hist_g + (size_t)chunk * NBUCK;
    for (int i = threadIdx.x; i < NBUCK; i += 1024) cur[i] = bstart[i] + hrow[i];
    __syncthreads();
    size_t e0 = (size_t)chunk * EPB;
    const int4* sp = (const int4*)(ei + e0);
    const int4* dp = (const int4*)(ei + N_EDGES + e0);
    for (int i = threadIdx.x; i < EPB / 4; i += 1024) {
        int4 s = sp[i];
        int4 d = dp[i];
        int p0 = atomicAdd(&cur[d.x >> BSH], 1);
        int p1 = atomicAdd(&cur[d.y >> BSH], 1);
        int p2 = atomicAdd(&cur[d.z >> BSH], 1);
        int p3 = atomicAdd(&cur[d.w >> BSH], 1);
        packed[p0] = (unsigned)s.x | ((unsigned)(d.x & DLM) << 17);
        packed[p1] = (unsigned)s.y | ((unsigned)(d.y & DLM) << 17);
        packed[p2] = (unsigned)s.z | ((unsigned)(d.z & DLM) << 17);
        packed[p3] = (unsigned)s.w | ((unsigned)(d.w & DLM) << 17);
    }
}

// ---------------------------------------------------------------------------
// Kernel 5 (fused sort+agg): one block per 64-dst bucket; packed read once
// into registers, LDS counting-sort, then 4-threads-per-dst aggregation
// with unroll-4 gather batching and fused epilogue.
__global__ __launch_bounds__(256) void k_aggsort(
        const unsigned* __restrict__ packed, const int* __restrict__ bstart,
        const float* __restrict__ el, const float* __restrict__ er,
        const unsigned short* __restrict__ featb, const float* __restrict__ res,
        const float* __restrict__ bias, float* __restrict__ out) {
    __shared__ int cnt[BUCK_W];
    __shared__ int off[BUCK_W];
    __shared__ unsigned srt[SORT_CAP];
    int b = blockIdx.x, t = threadIdx.x;
    int lo = bstart[b], hi = bstart[b + 1];

    if (t < BUCK_W) cnt[t] = 0;
    __syncthreads();

    unsigned pe[RCAP];
    int      tk[RCAP];
    #pragma unroll
    for (int i = 0; i < RCAP; i++) {
        int j = lo + i * 256 + t;
        if (j < hi) {
            unsigned p = packed[j];
            pe[i] = p;
            tk[i] = atomicAdd(&cnt[p >> 17], 1);
        } else {
            pe[i] = 0u; tk[i] = -1;
        }
    }
    __syncthreads();

    if (t < BUCK_W) off[t] = cnt[t];
    __syncthreads();
    #pragma unroll
    for (int d = 1; d < BUCK_W; d <<= 1) {
        int v = (t < BUCK_W && t >= d) ? off[t - d] : 0;
        __syncthreads();
        if (t < BUCK_W) off[t] += v;
        __syncthreads();
    }

    #pragma unroll
    for (int i = 0; i < RCAP; i++) {
        if (tk[i] >= 0) {
            int dl = (int)(pe[i] >> 17);
            srt[off[dl] - cnt[dl] + tk[i]] = pe[i] & 0x1FFFFu;
        }
    }
    __syncthreads();

    // Agg: 4 threads per dst (t = dl*4 + r)
    int dl = t >> 2, r = t & 3;
    int n = b * BUCK_W + dl;
    if (n >= N_NODES) return;
    int sBeg = off[dl] - cnt[dl];
    int sEnd = off[dl];
    float2 ern = *(const float2*)(er + n * 2);
    float den0 = 0.f, den1 = 0.f;
    float S[FH];
    #pragma unroll
    for (int k = 0; k < FH; k++) S[k] = 0.f;

    int j = sBeg + r;
    for (; j + 3 * TPD < sEnd; j += 4 * TPD) {
        int s0 = (int)srt[j];
        int s1 = (int)srt[j + TPD];
        int s2 = (int)srt[j + 2 * TPD];
        int s3 = (int)srt[j + 3 * TPD];
        float2 e0 = *(const float2*)(el + s0 * 2);
        float2 e1 = *(const float2*)(el + s1 * 2);
        float2 e2 = *(const float2*)(el + s2 * 2);
        float2 e3 = *(const float2*)(el + s3 * 2);
        const uint4* f0p = (const uint4*)(featb + (size_t)s0 * FH);
        const uint4* f1p = (const uint4*)(featb + (size_t)s1 * FH);
        const uint4* f2p = (const uint4*)(featb + (size_t)s2 * FH);
        const uint4* f3p = (const uint4*)(featb + (size_t)s3 * FH);
        uint4 u00 = f0p[0], u01 = f0p[1];
        uint4 u10 = f1p[0], u11 = f1p[1];
        uint4 u20 = f2p[0], u21 = f2p[1];
        uint4 u30 = f3p[0], u31 = f3p[1];
        float a0 = e0.x + ern.x, b0 = e0.y + ern.y;
        float a1 = e1.x + ern.x, b1 = e1.y + ern.y;
        float a2 = e2.x + ern.x, b2 = e2.y + ern.y;
        float a3 = e3.x + ern.x, b3 = e3.y + ern.y;
        a0 = a0 >= 0.f ? a0 : NEG_SLOPE * a0;  b0 = b0 >= 0.f ? b0 : NEG_SLOPE * b0;
        a1 = a1 >= 0.f ? a1 : NEG_SLOPE * a1;  b1 = b1 >= 0.f ? b1 : NEG_SLOPE * b1;
        a2 = a2 >= 0.f ? a2 : NEG_SLOPE * a2;  b2 = b2 >= 0.f ? b2 : NEG_SLOPE * b2;
        a3 = a3 >= 0.f ? a3 : NEG_SLOPE * a3;  b3 = b3 >= 0.f ? b3 : NEG_SLOPE * b3;
        float w00 = __expf(a0), w01 = __expf(b0);
        float w10 = __expf(a1), w11 = __expf(b1);
        float w20 = __expf(a2), w21 = __expf(b2);
        float w30 = __expf(a3), w31 = __expf(b3);
        den0 += w00 + w10 + w20 + w30;
        den1 += w01 + w11 + w21 + w31;
        S[0]  = fmaf(w00, bflo(u00.x), fmaf(w10, bflo(u10.x), fmaf(w20, bflo(u20.x), fmaf(w30, bflo(u30.x), S[0]))));
        S[1]  = fmaf(w00, bfhi(u00.x), fmaf(w10, bfhi(u10.x), fmaf(w20, bfhi(u20.x), fmaf(w30, bfhi(u30.x), S[1]))));
        S[2]  = fmaf(w00, bflo(u00.y), fmaf(w10, bflo(u10.y), fmaf(w20, bflo(u20.y), fmaf(w30, bflo(u30.y), S[2]))));
        S[3]  = fmaf(w00, bfhi(u00.y), fmaf(w10, bfhi(u10.y), fmaf(w20, bfhi(u20.y), fmaf(w30, bfhi(u30.y), S[3]))));
        S[4]  = fmaf(w00, bflo(u00.z), fmaf(w10, bflo(u10.z), fmaf(w20, bflo(u20.z), fmaf(w30, bflo(u30.z), S[4]))));
        S[5]  = fmaf(w00, bfhi(u00.z), fmaf(w10, bfhi(u10.z), fmaf(w20, bfhi(u20.z), fmaf(w30, bfhi(u30.z), S[5]))));
        S[6]  = fmaf(w00, bflo(u00.w), fmaf(w10, bflo(u10.w), fmaf(w20, bflo(u20.w), fmaf(w30, bflo(u30.w), S[6]))));
        S[7]  = fmaf(w00, bfhi(u00.w), fmaf(w10, bfhi(u10.w), fmaf(w20, bfhi(u20.w), fmaf(w30, bfhi(u30.w), S[7]))));
        S[8]  = fmaf(w01, bflo(u01.x), fmaf(w11, bflo(u11.x), fmaf(w21, bflo(u21.x), fmaf(w31, bflo(u31.x), S[8]))));
        S[9]  = fmaf(w01, bfhi(u01.x), fmaf(w11, bfhi(u11.x), fmaf(w21, bfhi(u21.x), fmaf(w31, bfhi(u31.x), S[9]))));
        S[10] = fmaf(w01, bflo(u01.y), fmaf(w11, bflo(u11.y), fmaf(w21, bflo(u21.y), fmaf(w31, bflo(u31.y), S[10]))));
        S[11] = fmaf(w01, bfhi(u01.y), fmaf(w11, bfhi(u11.y), fmaf(w21, bfhi(u21.y), fmaf(w31, bfhi(u31.y), S[11]))));
        S[12] = fmaf(w01, bflo(u01.z), fmaf(w11, bflo(u11.z), fmaf(w21, bflo(u21.z), fmaf(w31, bflo(u31.z), S[12]))));
        S[13] = fmaf(w01, bfhi(u01.z), fmaf(w11, bfhi(u11.z), fmaf(w21, bfhi(u21.z), fmaf(w31, bfhi(u31.z), S[13]))));
        S[14] = fmaf(w01, bflo(u01.w), fmaf(w11, bflo(u11.w), fmaf(w21, bflo(u21.w), fmaf(w31, bflo(u31.w), S[14]))));
        S[15] = fmaf(w01, bfhi(u01.w), fmaf(w11, bfhi(u11.w), fmaf(w21, bfhi(u21.w), fmaf(w31, bfhi(u31.w), S[15]))));
    }
    for (; j < sEnd; j += TPD) {
        int sa = (int)srt[j];
        float2 ea = *(const float2*)(el + sa * 2);
        float v0 = ea.x + ern.x, v1 = ea.y + ern.y;
        v0 = v0 >= 0.f ? v0 : NEG_SLOPE * v0;
        v1 = v1 >= 0.f ? v1 : NEG_SLOPE * v1;
        float w0 = __expf(v0), w1 = __expf(v1);
        den0 += w0; den1 += w1;
        const uint4* fp = (const uint4*)(featb + (size_t)sa * FH);
        uint4 u0 = fp[0], u1 = fp[1];
        S[0]  = fmaf(w0, bflo(u0.x), S[0]);  S[1]  = fmaf(w0, bfhi(u0.x), S[1]);
        S[2]  = fmaf(w0, bflo(u0.y), S[2]);  S[3]  = fmaf(w0, bfhi(u0.y), S[3]);
        S[4]  = fmaf(w0, bflo(u0.z), S[4]);  S[5]  = fmaf(w0, bfhi(u0.z), S[5]);
        S[6]  = fmaf(w0, bflo(u0.w), S[6]);  S[7]  = fmaf(w0, bfhi(u0.w), S[7]);
        S[8]  = fmaf(w1, bflo(u1.x), S[8]);  S[9]  = fmaf(w1, bfhi(u1.x), S[9]);
        S[10] = fmaf(w1, bflo(u1.y), S[10]); S[11] = fmaf(w1, bfhi(u1.y), S[11]);
        S[12] = fmaf(w1, bflo(u1.z), S[12]); S[13] = fmaf(w1, bfhi(u1.z), S[13]);
        S[14] = fmaf(w1, bflo(u1.w), S[14]); S[15] = fmaf(w1, bfhi(u1.w), S[15]);
    }

    // quad reduction (lanes 4k..4k+3 share one dst)
    #pragma unroll
    for (int k = 0; k < FH; k++) {
        S[k] += __shfl_xor(S[k], 1);
        S[k] += __shfl_xor(S[k], 2);
    }
    den0 += __shfl_xor(den0, 1); den0 += __shfl_xor(den0, 2);
    den1 += __shfl_xor(den1, 1); den1 += __shfl_xor(den1, 2);

    if (r == 0) {
        float inv0 = 1.f / fmaxf(den0, EPSF);
        float inv1 = 1.f / fmaxf(den1, EPSF);
        const float* rr = res + (size_t)n * FH;
        float4 r0a = *(const float4*)(rr + 0),  r0b = *(const float4*)(rr + 4);
        float4 r1a = *(const float4*)(rr + 8),  r1b = *(const float4*)(rr + 12);
        float4 oa, ob;
        oa.x = 0.5f * ((S[0] * inv0 + r0a.x + bias[0])  + (S[8]  * inv1 + r1a.x + bias[8]));
        oa.y = 0.5f * ((S[1] * inv0 + r0a.y + bias[1])  + (S[9]  * inv1 + r1a.y + bias[9]));
        oa.z = 0.5f * ((S[2] * inv0 + r0a.z + bias[2])  + (S[10] * inv1 + r1a.z + bias[10]));
        oa.w = 0.5f * ((S[3] * inv0 + r0a.w + bias[3])  + (S[11] * inv1 + r1a.w + bias[11]));
        ob.x = 0.5f * ((S[4] * inv0 + r0b.x + bias[4])  + (S[12] * inv1 + r1b.x + bias[12]));
        ob.y = 0.5f * ((S[5] * inv0 + r0b.y + bias[5])  + (S[13] * inv1 + r1b.y + bias[13]));
        ob.z = 0.5f * ((S[6] * inv0 + r0b.z + bias[6])  + (S[14] * inv1 + r1b.z + bias[14]));
        ob.w = 0.5f * ((S[7] * inv0 + r0b.w + bias[7])  + (S[15] * inv1 + r1b.w + bias[15]));
        *(float4*)(out + (size_t)n * NC + 0) = oa;
        *(float4*)(out + (size_t)n * NC + 4) = ob;
    }
}

extern "C" void kernel_launch(void* const* d_in, const int* in_sizes, int n_in,
                              void* d_out, int out_size, void* d_ws, size_t ws_size,
                              hipStream_t stream) {
    const float* x      = (const float*)d_in[0];
    const int*   ei     = (const int*)d_in[1];
    const float* W      = (const float*)d_in[2];
    const float* attn_l = (const float*)d_in[3];
    const float* attn_r = (const float*)d_in[4];
    const float* bias   = (const float*)d_in[5];
    const float* Wres   = (const float*)d_in[6];
    float* out = (float*)d_out;

    char* ws = (char*)d_ws;
    const size_t szFB   = (size_t)N_NODES * FH * sizeof(unsigned short); // 3.2 MB
    const size_t szNF   = (size_t)N_NODES * FH * sizeof(float);          // 6.4 MB
    const size_t szNH   = (size_t)N_NODES * HEADS * sizeof(float);       // 0.8 MB
    const size_t szHist = (((size_t)B1 * NBUCK * sizeof(int)) + 255) & ~(size_t)255;
    const size_t szBt   = 8192;
    size_t off = 0;
    unsigned short* featb = (unsigned short*)(ws + off); off += szFB;
    float*    res    = (float*)(ws + off); off += szNF;
    float*    el     = (float*)(ws + off); off += szNH;
    float*    er     = (float*)(ws + off); off += szNH;
    int*      hist_g = (int*)  (ws + off); off += szHist;
    int*      btot   = (int*)  (ws + off); off += szBt;
    int*      bstart = (int*)  (ws + off); off += szBt;
    unsigned* packed = (unsigned*)(ws + off); off += (size_t)N_EDGES * sizeof(unsigned);

    // 1563 blocks: node transform everywhere + histogram in blocks 0..255
    k_node<<<(N_NODES / 16 + 3) / 4, 256, 0, stream>>>(x, W, Wres, attn_l, attn_r,
                                                       ei, featb, res, el, er, hist_g);
    k_scan1<<<NBUCK, 64, 0, stream>>>(hist_g, btot);
    k_scan2<<<1, 1024, 0, stream>>>(btot, bstart);
    k_scatter2<<<B1, 1024, 0, stream>>>(ei, hist_g, bstart, packed);
    k_aggsort<<<NBUCK, 256, 0, stream>>>(packed, bstart, el, er, featb, res, bias, out);
}

// Round 16
// 108.312 us; speedup vs baseline: 1.1121x; 1.0147x over previous
//
#include <hip/hip_runtime.h>
#include <hip/hip_bf16.h>
#include <math.h>

#define N_NODES 100000
#define N_EDGES 3200000
#define IN_FEAT 256
#define HEADS 2
#define NC 8
#define FH 16               // HEADS*NC
#define NEG_SLOPE 0.2f
#define EPSF 1e-15f

// Bucketed partition: 64 dsts per bucket.
#define BSH 6
#define BUCK_W 64
#define DLM 63
#define NBUCK ((N_NODES + BUCK_W - 1) / BUCK_W)   // 1563
#define B1 256                                    // partition chunks (8 XCDs x 32)
#define EPB (N_EDGES / B1)                        // 12500 edges/chunk (exact)

// Fused sort+agg: LDS capacity per bucket (mean 2048, sd 45; +11 sd margin).
#define SORT_CAP 2560
#define RCAP (SORT_CAP / 256)    // 10 register-cached records per thread
#define TPD 4                    // threads per dst in agg phase

typedef float f32x4 __attribute__((ext_vector_type(4)));
typedef short bf16x8 __attribute__((ext_vector_type(8)));

// fp32 -> bf16 (RNE) via the native conversion path (compiler emits cvt ops,
// ~1 VALU/elem vs 3 for manual bit-twiddling).
__device__ __forceinline__ short f2bfs(float f) {
    union { __hip_bfloat16 h; short s; } u;
    u.h = __float2bfloat16(f);
    return u.s;
}
__device__ __forceinline__ float bflo(unsigned u) { return __uint_as_float(u << 16); }
__device__ __forceinline__ float bfhi(unsigned u) { return __uint_as_float(u & 0xFFFF0000u); }

// XCD-grouped bijective chunk map (8 XCDs x 32 chunks): each XCD owns a
// contiguous chunk range -> its packed-runs in every bucket segment are
// contiguous and L2-local (no cross-XCD dirty-line sharing).
__device__ __forceinline__ int chunk_of_block(int bid) {
    return (bid & 7) * (B1 / 8) + (bid >> 3);
}

// ---------------------------------------------------------------------------
// Kernel 1 (MFMA node transform + FUSED histogram): 1563 blocks.
// All blocks: one wave per 16 nodes; D[16x32] = bf16(x)@bf16([W|Wres]).
// Blocks 0..B1-1 additionally histogram their edge chunk.
__global__ __launch_bounds__(256) void k_node(
        const float* __restrict__ x, const float* __restrict__ W,
        const float* __restrict__ Wres, const float* __restrict__ attn_l,
        const float* __restrict__ attn_r, const int* __restrict__ ei,
        unsigned short* __restrict__ featb, float* __restrict__ res,
        float* __restrict__ el, float* __restrict__ er,
        int* __restrict__ hist_g) {
    __shared__ int h[NBUCK];
    int t = threadIdx.x;
    bool do_count = (blockIdx.x < B1);
    if (do_count) {
        for (int i = t; i < NBUCK; i += 256) h[i] = 0;
    }

    // ---- node phase (wave-granular guard; no returns, shuffles wave-uniform)
    int wid = (blockIdx.x * 256 + t) >> 6;
    int n0 = wid * 16;
    if (n0 < N_NODES) {
        int l   = t & 63;
        int col = l & 15;
        int g   = l >> 4;

        bf16x8 bw[8], bq[8];
        #pragma unroll
        for (int kk = 0; kk < 8; kk++) {
            #pragma unroll
            for (int j = 0; j < 8; j++) {
                int k = kk * 32 + g * 8 + j;
                bw[kk][j] = f2bfs(W[k * FH + col]);
                bq[kk][j] = f2bfs(Wres[k * FH + col]);
            }
        }

        const float* xr = x + (size_t)(n0 + col) * IN_FEAT;
        f32x4 acc0 = {0.f, 0.f, 0.f, 0.f};
        f32x4 acc1 = {0.f, 0.f, 0.f, 0.f};
        float ss = 0.f;
        #pragma unroll
        for (int kk = 0; kk < 8; kk++) {
            float4 v0 = *(const float4*)(xr + kk * 32 + g * 8);
            float4 v1 = *(const float4*)(xr + kk * 32 + g * 8 + 4);
            ss += v0.x * v0.x + v0.y * v0.y + v0.z * v0.z + v0.w * v0.w
                + v1.x * v1.x + v1.y * v1.y + v1.z * v1.z + v1.w * v1.w;
            bf16x8 a;
            a[0] = f2bfs(v0.x); a[1] = f2bfs(v0.y);
            a[2] = f2bfs(v0.z); a[3] = f2bfs(v0.w);
            a[4] = f2bfs(v1.x); a[5] = f2bfs(v1.y);
            a[6] = f2bfs(v1.z); a[7] = f2bfs(v1.w);
            acc0 = __builtin_amdgcn_mfma_f32_16x16x32_bf16(a, bw[kk], acc0, 0, 0, 0);
            acc1 = __builtin_amdgcn_mfma_f32_16x16x32_bf16(a, bq[kk], acc1, 0, 0, 0);
        }

        ss += __shfl_xor(ss, 16);
        ss += __shfl_xor(ss, 32);
        float norm = fmaxf(sqrtf(ss), EPSF);
        float z = fminf(norm, 1.f - 1e-7f);
        float at = 0.5f * (log1pf(z) - log1pf(-z));   // artanh(clip)
        float scale = at / norm;

        float alc = attn_l[col], arc = attn_r[col];

        #pragma unroll
        for (int i = 0; i < 4; i++) {
            int ri = g * 4 + i;
            float s_i = __shfl(scale, ri);
            int nr = n0 + ri;
            float f_i = acc0[i] * s_i;
            float q_i = acc1[i] * s_i;
            featb[(size_t)nr * FH + col] = (unsigned short)f2bfs(f_i);
            res  [(size_t)nr * FH + col] = q_i;
            float pl = f_i * alc, pr = f_i * arc;
            float pl0 = (col < 8) ? pl : 0.f, pl1 = (col < 8) ? 0.f : pl;
            float pr0 = (col < 8) ? pr : 0.f, pr1 = (col < 8) ? 0.f : pr;
            #pragma unroll
            for (int m = 1; m < 16; m <<= 1) {
                pl0 += __shfl_xor(pl0, m); pl1 += __shfl_xor(pl1, m);
                pr0 += __shfl_xor(pr0, m); pr1 += __shfl_xor(pr1, m);
            }
            if (col == 0) {
                *(float2*)(el + nr * 2) = make_float2(pl0, pl1);
                *(float2*)(er + nr * 2) = make_float2(pr0, pr1);
            }
        }
    }

    // ---- count phase (blocks 0..B1-1 only; all threads alive)
    if (do_count) {
        __syncthreads();                    // h[] zeroing complete
        int chunk = chunk_of_block(blockIdx.x);
        const int4* dp = (const int4*)(ei + N_EDGES + (size_t)chunk * EPB);
        for (int i = t; i < EPB / 4; i += 256) {
            int4 d = dp[i];
            atomicAdd(&h[d.x >> BSH], 1);
            atomicAdd(&h[d.y >> BSH], 1);
            atomicAdd(&h[d.z >> BSH], 1);
            atomicAdd(&h[d.w >> BSH], 1);
        }
        __syncthreads();
        int* outp = hist_g + (size_t)chunk * NBUCK;
        for (int i = t; i < NBUCK; i += 256) outp[i] = h[i];
    }
}

// ---------------------------------------------------------------------------
// Kernel 2: per-bucket exclusive scan over the B1 chunks (in place) + totals.
__global__ __launch_bounds__(64) void k_scan1(int* __restrict__ hist_g,
                                              int* __restrict__ btot) {
    __shared__ int sm[64];
    int bucket = blockIdx.x;
    int t = threadIdx.x;
    int carry = 0;
    for (int base = 0; base < B1; base += 64) {
        int blk = base + t;
        int v = hist_g[(size_t)blk * NBUCK + bucket];       // B1 % 64 == 0
        __syncthreads();
        sm[t] = v;
        __syncthreads();
        for (int off = 1; off < 64; off <<= 1) {
            int u = (t >= off) ? sm[t - off] : 0;
            __syncthreads();
            sm[t] += u;
            __syncthreads();
        }
        hist_g[(size_t)blk * NBUCK + bucket] = carry + sm[t] - v;
        carry += sm[63];
    }
    if (t == 0) btot[bucket] = carry;
}

// ---------------------------------------------------------------------------
// Kernel 3: scatter edges into bucket regions. Each block redundantly
// LDS-scans btot (hidden under 16-wave occupancy) -> bucket starts; block 0
// publishes bstart for k_aggsort. Deletes the separate k_scan2 dispatch.
// Record: src (17 bits) | dst_local (6 bits) << 17. Chunk map = XCD-grouped.
__global__ __launch_bounds__(1024) void k_scatter2(const int* __restrict__ ei,
                                                   const int* __restrict__ hist_g,
                                                   const int* __restrict__ btot,
                                                   int* __restrict__ bstart_g,
                                                   unsigned* __restrict__ packed) {
    __shared__ int sm[2048];
    __shared__ int cur[NBUCK];
    int t = threadIdx.x;
    int chunk = chunk_of_block(blockIdx.x);
    const int* hrow = hist_g + (size_t)chunk * NBUCK;

    // bucket-start scan (2 elements per thread over 2048-wide Hillis-Steele)
    int i0 = t, i1 = t + 1024;
    int v0 = (i0 < NBUCK) ? btot[i0] : 0;
    int v1 = (i1 < NBUCK) ? btot[i1] : 0;
    sm[i0] = v0; sm[i1] = v1;
    __syncthreads();
    for (int d = 1; d < 2048; d <<= 1) {
        int a0 = (i0 >= d) ? sm[i0 - d] : 0;
        int a1 = (i1 >= d) ? sm[i1 - d] : 0;
        __syncthreads();
        sm[i0] += a0; sm[i1] += a1;
        __syncthreads();
    }
    if (i0 < NBUCK) cur[i0] = sm[i0] - v0 + hrow[i0];
    if (i1 < NBUCK) cur[i1] = sm[i1] - v1 + hrow[i1];
    if (blockIdx.x == 0) {
        if (i0 < NBUCK) bstart_g[i0] = sm[i0] - v0;
        if (i1 < NBUCK) bstart_g[i1] = sm[i1] - v1;
        if (t == 0) bstart_g[NBUCK] = sm[2047];   // = N_EDGES
    }
    __syncthreads();

    size_t e0 = (size_t)chunk * EPB;
    const int4* sp = (const int4*)(ei + e0);
    const int4* dp = (const int4*)(ei + N_EDGES + e0);
    for (int i = t; i < EPB / 4; i += 1024) {
        int4 s = sp[i];
        int4 d = dp[i];
        int p0 = atomicAdd(&cur[d.x >> BSH], 1);
        int p1 = atomicAdd(&cur[d.y >> BSH], 1);
        int p2 = atomicAdd(&cur[d.z >> BSH], 1);
        int p3 = atomicAdd(&cur[d.w >> BSH], 1);
        packed[p0] = (unsigned)s.x | ((unsigned)(d.x & DLM) << 17);
        packed[p1] = (unsigned)s.y | ((unsigned)(d.y & DLM) << 17);
        packed[p2] = (unsigned)s.z | ((unsigned)(d.z & DLM) << 17);
        packed[p3] = (unsigned)s.w | ((unsigned)(d.w & DLM) << 17);
    }
}

// ---------------------------------------------------------------------------
// Kernel 4 (fused sort+agg): one block per 64-dst bucket; packed read once
// into registers, LDS counting-sort, then 4-threads-per-dst aggregation
// with unroll-4 gather batching and fused epilogue.
__global__ __launch_bounds__(256) void k_aggsort(
        const unsigned* __restrict__ packed, const int* __restrict__ bstart,
        const float* __restrict__ el, const float* __restrict__ er,
        const unsigned short* __restrict__ featb, const float* __restrict__ res,
        const float* __restrict__ bias, float* __restrict__ out) {
    __shared__ int cnt[BUCK_W];
    __shared__ int off[BUCK_W];
    __shared__ unsigned srt[SORT_CAP];
    int b = blockIdx.x, t = threadIdx.x;
    int lo = bstart[b], hi = bstart[b + 1];

    if (t < BUCK_W) cnt[t] = 0;
    __syncthreads();

    unsigned pe[RCAP];
    int      tk[RCAP];
    #pragma unroll
    for (int i = 0; i < RCAP; i++) {
        int j = lo + i * 256 + t;
        if (j < hi) {
            unsigned p = packed[j];
            pe[i] = p;
            tk[i] = atomicAdd(&cnt[p >> 17], 1);
        } else {
            pe[i] = 0u; tk[i] = -1;
        }
    }
    __syncthreads();

    if (t < BUCK_W) off[t] = cnt[t];
    __syncthreads();
    #pragma unroll
    for (int d = 1; d < BUCK_W; d <<= 1) {
        int v = (t < BUCK_W && t >= d) ? off[t - d] : 0;
        __syncthreads();
        if (t < BUCK_W) off[t] += v;
        __syncthreads();
    }

    #pragma unroll
    for (int i = 0; i < RCAP; i++) {
        if (tk[i] >= 0) {
            int dl = (int)(pe[i] >> 17);
            srt[off[dl] - cnt[dl] + tk[i]] = pe[i] & 0x1FFFFu;
        }
    }
    __syncthreads();

    // Agg: 4 threads per dst (t = dl*4 + r)
    int dl = t >> 2, r = t & 3;
    int n = b * BUCK_W + dl;
    if (n >= N_NODES) return;
    int sBeg = off[dl] - cnt[dl];
    int sEnd = off[dl];
    float2 ern = *(const float2*)(er + n * 2);
    float den0 = 0.f, den1 = 0.f;
    float S[FH];
    #pragma unroll
    for (int k = 0; k < FH; k++) S[k] = 0.f;

    int j = sBeg + r;
    for (; j + 3 * TPD < sEnd; j += 4 * TPD) {
        int s0 = (int)srt[j];
        int s1 = (int)srt[j + TPD];
        int s2 = (int)srt[j + 2 * TPD];
        int s3 = (int)srt[j + 3 * TPD];
        float2 e0 = *(const float2*)(el + s0 * 2);
        float2 e1 = *(const float2*)(el + s1 * 2);
        float2 e2 = *(const float2*)(el + s2 * 2);
        float2 e3 = *(const float2*)(el + s3 * 2);
        const uint4* f0p = (const uint4*)(featb + (size_t)s0 * FH);
        const uint4* f1p = (const uint4*)(featb + (size_t)s1 * FH);
        const uint4* f2p = (const uint4*)(featb + (size_t)s2 * FH);
        const uint4* f3p = (const uint4*)(featb + (size_t)s3 * FH);
        uint4 u00 = f0p[0], u01 = f0p[1];
        uint4 u10 = f1p[0], u11 = f1p[1];
        uint4 u20 = f2p[0], u21 = f2p[1];
        uint4 u30 = f3p[0], u31 = f3p[1];
        float a0 = e0.x + ern.x, b0 = e0.y + ern.y;
        float a1 = e1.x + ern.x, b1 = e1.y + ern.y;
        float a2 = e2.x + ern.x, b2 = e2.y + ern.y;
        float a3 = e3.x + ern.x, b3 = e3.y + ern.y;
        a0 = a0 >= 0.f ? a0 : NEG_SLOPE * a0;  b0 = b0 >= 0.f ? b0 : NEG_SLOPE * b0;
        a1 = a1 >= 0.f ? a1 : NEG_SLOPE * a1;  b1 = b1 >= 0.f ? b1 : NEG_SLOPE * b1;
        a2 = a2 >= 0.f ? a2 : NEG_SLOPE * a2;  b2 = b2 >= 0.f ? b2 : NEG_SLOPE * b2;
        a3 = a3 >= 0.f ? a3 : NEG_SLOPE * a3;  b3 = b3 >= 0.f ? b3 : NEG_SLOPE * b3;
        float w00 = __expf(a0), w01 = __expf(b0);
        float w10 = __expf(a1), w11 = __expf(b1);
        float w20 = __expf(a2), w21 = __expf(b2);
        float w30 = __expf(a3), w31 = __expf(b3);
        den0 += w00 + w10 + w20 + w30;
        den1 += w01 + w11 + w21 + w31;
        S[0]  = fmaf(w00, bflo(u00.x), fmaf(w10, bflo(u10.x), fmaf(w20, bflo(u20.x), fmaf(w30, bflo(u30.x), S[0]))));
        S[1]  = fmaf(w00, bfhi(u00.x), fmaf(w10, bfhi(u10.x), fmaf(w20, bfhi(u20.x), fmaf(w30, bfhi(u30.x), S[1]))));
        S[2]  = fmaf(w00, bflo(u00.y), fmaf(w10, bflo(u10.y), fmaf(w20, bflo(u20.y), fmaf(w30, bflo(u30.y), S[2]))));
        S[3]  = fmaf(w00, bfhi(u00.y), fmaf(w10, bfhi(u10.y), fmaf(w20, bfhi(u20.y), fmaf(w30, bfhi(u30.y), S[3]))));
        S[4]  = fmaf(w00, bflo(u00.z), fmaf(w10, bflo(u10.z), fmaf(w20, bflo(u20.z), fmaf(w30, bflo(u30.z), S[4]))));
        S[5]  = fmaf(w00, bfhi(u00.z), fmaf(w10, bfhi(u10.z), fmaf(w20, bfhi(u20.z), fmaf(w30, bfhi(u30.z), S[5]))));
        S[6]  = fmaf(w00, bflo(u00.w), fmaf(w10, bflo(u10.w), fmaf(w20, bflo(u20.w), fmaf(w30, bflo(u30.w), S[6]))));
        S[7]  = fmaf(w00, bfhi(u00.w), fmaf(w10, bfhi(u10.w), fmaf(w20, bfhi(u20.w), fmaf(w30, bfhi(u30.w), S[7]))));
        S[8]  = fmaf(w01, bflo(u01.x), fmaf(w11, bflo(u11.x), fmaf(w21, bflo(u21.x), fmaf(w31, bflo(u31.x), S[8]))));
        S[9]  = fmaf(w01, bfhi(u01.x), fmaf(w11, bfhi(u11.x), fmaf(w21, bfhi(u21.x), fmaf(w31, bfhi(u31.x), S[9]))));
        S[10] = fmaf(w01, bflo(u01.y), fmaf(w11, bflo(u11.y), fmaf(w21, bflo(u21.y), fmaf(w31, bflo(u31.y), S[10]))));
        S[11] = fmaf(w01, bfhi(u01.y), fmaf(w11, bfhi(u11.y), fmaf(w21, bfhi(u21.y), fmaf(w31, bfhi(u31.y), S[11]))));
        S[12] = fmaf(w01, bflo(u01.z), fmaf(w11, bflo(u11.z), fmaf(w21, bflo(u21.z), fmaf(w31, bflo(u31.z), S[12]))));
        S[13] = fmaf(w01, bfhi(u01.z), fmaf(w11, bfhi(u11.z), fmaf(w21, bfhi(u21.z), fmaf(w31, bfhi(u31.z), S[13]))));
        S[14] = fmaf(w01, bflo(u01.w), fmaf(w11, bflo(u11.w), fmaf(w21, bflo(u21.w), fmaf(w31, bflo(u31.w), S[14]))));
        S[15] = fmaf(w01, bfhi(u01.w), fmaf(w11, bfhi(u11.w), fmaf(w21, bfhi(u21.w), fmaf(w31, bfhi(u31.w), S[15]))));
    }
    for (; j < sEnd; j += TPD) {
        int sa = (int)srt[j];
        float2 ea = *(const float2*)(el + sa * 2);
        float v0 = ea.x + ern.x, v1 = ea.y + ern.y;
        v0 = v0 >= 0.f ? v0 : NEG_SLOPE * v0;
        v1 = v1 >= 0.f ? v1 : NEG_SLOPE * v1;
        float w0 = __expf(v0), w1 = __expf(v1);
        den0 += w0; den1 += w1;
        const uint4* fp = (const uint4*)(featb + (size_t)sa * FH);
        uint4 u0 = fp[0], u1 = fp[1];
        S[0]  = fmaf(w0, bflo(u0.x), S[0]);  S[1]  = fmaf(w0, bfhi(u0.x), S[1]);
        S[2]  = fmaf(w0, bflo(u0.y), S[2]);  S[3]  = fmaf(w0, bfhi(u0.y), S[3]);
        S[4]  = fmaf(w0, bflo(u0.z), S[4]);  S[5]  = fmaf(w0, bfhi(u0.z), S[5]);
        S[6]  = fmaf(w0, bflo(u0.w), S[6]);  S[7]  = fmaf(w0, bfhi(u0.w), S[7]);
        S[8]  = fmaf(w1, bflo(u1.x), S[8]);  S[9]  = fmaf(w1, bfhi(u1.x), S[9]);
        S[10] = fmaf(w1, bflo(u1.y), S[10]); S[11] = fmaf(w1, bfhi(u1.y), S[11]);
        S[12] = fmaf(w1, bflo(u1.z), S[12]); S[13] = fmaf(w1, bfhi(u1.z), S[13]);
        S[14] = fmaf(w1, bflo(u1.w), S[14]); S[15] = fmaf(w1, bfhi(u1.w), S[15]);
    }

    // quad reduction (lanes 4k..4k+3 share one dst)
    #pragma unroll
    for (int k = 0; k < FH; k++) {
        S[k] += __shfl_xor(S[k], 1);
        S[k] += __shfl_xor(S[k], 2);
    }
    den0 += __shfl_xor(den0, 1); den0 += __shfl_xor(den0, 2);
    den1 += __shfl_xor(den1, 1); den1 += __shfl_xor(den1, 2);

    if (r == 0) {
        float inv0 = 1.f / fmaxf(den0, EPSF);
        float inv1 = 1.f / fmaxf(den1, EPSF);
        const float* rr = res + (size_t)n * FH;
        float4 r0a = *(const float4*)(rr + 0),  r0b = *(const float4*)(rr + 4);
        float4 r1a = *(const float4*)(rr + 8),  r1b = *(const float4*)(rr + 12);
        float4 oa, ob;
        oa.x = 0.5f * ((S[0] * inv0 + r0a.x + bias[0])  + (S[8]  * inv1 + r1a.x + bias[8]));
        oa.y = 0.5f * ((S[1] * inv0 + r0a.y + bias[1])  + (S[9]  * inv1 + r1a.y + bias[9]));
        oa.z = 0.5f * ((S[2] * inv0 + r0a.z + bias[2])  + (S[10] * inv1 + r1a.z + bias[10]));
        oa.w = 0.5f * ((S[3] * inv0 + r0a.w + bias[3])  + (S[11] * inv1 + r1a.w + bias[11]));
        ob.x = 0.5f * ((S[4] * inv0 + r0b.x + bias[4])  + (S[12] * inv1 + r1b.x + bias[12]));
        ob.y = 0.5f * ((S[5] * inv0 + r0b.y + bias[5])  + (S[13] * inv1 + r1b.y + bias[13]));
        ob.z = 0.5f * ((S[6] * inv0 + r0b.z + bias[6])  + (S[14] * inv1 + r1b.z + bias[14]));
        ob.w = 0.5f * ((S[7] * inv0 + r0b.w + bias[7])  + (S[15] * inv1 + r1b.w + bias[15]));
        *(float4*)(out + (size_t)n * NC + 0) = oa;
        *(float4*)(out + (size_t)n * NC + 4) = ob;
    }
}

extern "C" void kernel_launch(void* const* d_in, const int* in_sizes, int n_in,
                              void* d_out, int out_size, void* d_ws, size_t ws_size,
                              hipStream_t stream) {
    const float* x      = (const float*)d_in[0];
    const int*   ei     = (const int*)d_in[1];
    const float* W      = (const float*)d_in[2];
    const float* attn_l = (const float*)d_in[3];
    const float* attn_r = (const float*)d_in[4];
    const float* bias   = (const float*)d_in[5];
    const float* Wres   = (const float*)d_in[6];
    float* out = (float*)d_out;

    char* ws = (char*)d_ws;
    const size_t szFB   = (size_t)N_NODES * FH * sizeof(unsigned short); // 3.2 MB
    const size_t szNF   = (size_t)N_NODES * FH * sizeof(float);          // 6.4 MB
    const size_t szNH   = (size_t)N_NODES * HEADS * sizeof(float);       // 0.8 MB
    const size_t szHist = (((size_t)B1 * NBUCK * sizeof(int)) + 255) & ~(size_t)255;
    const size_t szBt   = 8192;
    size_t off = 0;
    unsigned short* featb = (unsigned short*)(ws + off); off += szFB;
    float*    res    = (float*)(ws + off); off += szNF;
    float*    el     = (float*)(ws + off); off += szNH;
    float*    er     = (float*)(ws + off); off += szNH;
    int*      hist_g = (int*)  (ws + off); off += szHist;
    int*      btot   = (int*)  (ws + off); off += szBt;
    int*      bstart = (int*)  (ws + off); off += szBt;
    unsigned* packed = (unsigned*)(ws + off); off += (size_t)N_EDGES * sizeof(unsigned);

    // 1563 blocks: node transform everywhere + histogram in blocks 0..255
    k_node<<<(N_NODES / 16 + 3) / 4, 256, 0, stream>>>(x, W, Wres, attn_l, attn_r,
                                                       ei, featb, res, el, er, hist_g);
    k_scan1<<<NBUCK, 64, 0, stream>>>(hist_g, btot);
    k_scatter2<<<B1, 1024, 0, stream>>>(ei, hist_g, btot, bstart, packed);
    k_aggsort<<<NBUCK, 256, 0, stream>>>(packed, bstart, el, er, featb, res, bias, out);
}